// Round 12
// baseline (799.485 us; speedup 1.0000x reference)
//
#include <hip/hip_runtime.h>
#include <math.h>

// Problem constants (fixed by the reference setup_inputs)
#define BATCH 32
#define CH    192
#define TFEAT 2048
#define TTXT  512
#define NEGINF (-1e9f)

#define ATTN_ELEMS ((size_t)BATCH * TFEAT * TTXT)   // 33,554,432
#define DUR_OFF    ATTN_ELEMS
#define NEG_OFF    (ATTN_ELEMS + (size_t)BATCH * TTXT)

__device__ __forceinline__ void gload_lds16(const float* g, float* l) {
  __builtin_amdgcn_global_load_lds(
      (const __attribute__((address_space(1))) void*)g,
      (__attribute__((address_space(3))) void*)l, 16, 0, 0);
}

#define VMCNT(n) asm volatile("s_waitcnt vmcnt(" #n ")" ::: "memory")

// ---------------------------------------------------------------------------
// Kernel P: W1[b,c,s] = m*exp(-2*logs), W2[b,c,s] = -0.5*exp(-2*logs)
// ---------------------------------------------------------------------------
__global__ void k_prep(const float* __restrict__ m_p,
                       const float* __restrict__ logs_p,
                       float* __restrict__ w1, float* __restrict__ w2) {
  int gid = blockIdx.x * 256 + threadIdx.x;    // 0 .. 3,145,727
  float m = m_p[gid];
  float l = logs_p[gid];
  float r = __expf(-2.0f * l);
  w1[gid] = m * r;
  w2[gid] = -0.5f * r;
}

// ---------------------------------------------------------------------------
// Kernel A: cadd[b][s] = sum_c(-0.5*log(2pi) - logs) + sum_c(-0.5*m^2*r)
// ---------------------------------------------------------------------------
__global__ void k_cadd(const float* __restrict__ m_p,
                       const float* __restrict__ logs_p,
                       float* __restrict__ cadd) {
  int gid = blockIdx.x * 256 + threadIdx.x;        // 0 .. 16383
  int b = gid >> 9, s = gid & (TTXT - 1);
  const float* mp = m_p    + (size_t)b * CH * TTXT + s;
  const float* lp = logs_p + (size_t)b * CH * TTXT + s;
  float acc = -0.5f * 1.8378770664093453f * (float)CH;   // -C/2 * log(2*pi)
  #pragma unroll 4
  for (int c = 0; c < CH; ++c) {
    float l = lp[(size_t)c * TTXT];
    float m = mp[(size_t)c * TTXT];
    float r = __expf(-2.0f * l);
    acc -= l + 0.5f * m * m * r;
  }
  cadd[gid] = acc;
}

// ---------------------------------------------------------------------------
// Kernel B: fp32 vector GEMM, 512 threads, acc[8][4].
// R11 counters: VALUBusy 52%, zero spill — LDS(256cy/kk/CU) and VALU
// (256cy/kk/CU) co-limited, per-wave read->wait->fma chain wastes the rest.
// R12: explicit depth-1 fragment pipeline (two named Frag sets; kk+1 reads
// issued before kk's FMAs; sched_barrier(0) caps depth -> no spill blowup).
// Same ko/kk/fma order -> neg bit-identical.
// ---------------------------------------------------------------------------
#define BM 128
#define BN 128
#define BK 16

struct Frag { float a[8]; float p[4]; float q[4]; };

__global__ __launch_bounds__(512)
void k_gemm(const float* __restrict__ z_p,
            const float* __restrict__ w1g, const float* __restrict__ w2g,
            const float* __restrict__ cadd, float* __restrict__ neg) {
  __shared__ float Az[2][BK][BM];
  __shared__ float B1[2][BK][BN];
  __shared__ float B2[2][BK][BN];

  // chunked XCD swizzle (2048 blocks, 8 XCDs, 256 per chunk; bijective)
  int blk = (blockIdx.x & 7) * 256 + (blockIdx.x >> 3);
  int sb = blk & 3;            // TTXT/BN = 4
  int tb = (blk >> 2) & 15;    // TFEAT/BM = 16
  int b  = blk >> 6;
  int tid = threadIdx.x;
  int tx = tid & 31;           // col group: 4 cols at tx*4
  int ty = tid >> 5;           // row group: 8 rows at ty*8  (0..15)
  int wid  = tid >> 6;         // wave 0..7
  int lane = tid & 63;
  int lr = lane >> 5;          // row-within-pair
  int lc = (lane & 31) * 4;    // col (float4 granularity)

  const float* zb  = z_p + (size_t)b * CH * TFEAT + (size_t)tb * BM;
  const float* w1b = w1g + (size_t)b * CH * TTXT  + (size_t)sb * BN;
  const float* w2b = w2g + (size_t)b * CH * TTXT  + (size_t)sb * BN;

  auto STAGE = [&](int buf, int ko) {
    int kr = ko * BK + 2 * wid + lr;     // per-lane global k-row
    int kd = 2 * wid;                    // wave-uniform LDS row base
    gload_lds16(zb  + (size_t)kr * TFEAT + lc, &Az[buf][kd][0]);
    gload_lds16(w1b + (size_t)kr * TTXT  + lc, &B1[buf][kd][0]);
    gload_lds16(w2b + (size_t)kr * TTXT  + lc, &B2[buf][kd][0]);
  };
  auto LOADF = [&](Frag& f, int cur, int kk) {
    float4 a0 = *(const float4*)&Az[cur][kk][ty * 8];
    float4 a1 = *(const float4*)&Az[cur][kk][ty * 8 + 4];
    float4 p  = *(const float4*)&B1[cur][kk][tx * 4];
    float4 q  = *(const float4*)&B2[cur][kk][tx * 4];
    f.a[0]=a0.x; f.a[1]=a0.y; f.a[2]=a0.z; f.a[3]=a0.w;
    f.a[4]=a1.x; f.a[5]=a1.y; f.a[6]=a1.z; f.a[7]=a1.w;
    f.p[0]=p.x;  f.p[1]=p.y;  f.p[2]=p.z;  f.p[3]=p.w;
    f.q[0]=q.x;  f.q[1]=q.y;  f.q[2]=q.z;  f.q[3]=q.w;
  };

  float acc[8][4];
  #pragma unroll
  for (int i = 0; i < 8; ++i)
    #pragma unroll
    for (int j = 0; j < 4; ++j) acc[i][j] = 0.0f;

  auto FMAF = [&](const Frag& f) {
    #pragma unroll
    for (int i = 0; i < 8; ++i)
      #pragma unroll
      for (int j = 0; j < 4; ++j)
        acc[i][j] = fmaf(f.a[i], fmaf(f.a[i], f.q[j], f.p[j]), acc[i][j]);
  };

  STAGE(0, 0);
  VMCNT(0);
  __builtin_amdgcn_s_barrier();

  for (int ko = 0; ko < CH / BK; ++ko) {
    int cur = ko & 1;
    if (ko + 1 < CH / BK) STAGE(cur ^ 1, ko + 1);   // prefetch next tile

    Frag f0, f1;
    LOADF(f0, cur, 0);
    #pragma unroll
    for (int kk = 0; kk < BK; kk += 2) {
      LOADF(f1, cur, kk + 1);            // reads hide under FMAF(f0)
      FMAF(f0);
      __builtin_amdgcn_sched_barrier(0);
      if (kk + 2 < BK) LOADF(f0, cur, kk + 2);
      FMAF(f1);
      __builtin_amdgcn_sched_barrier(0);
    }
    VMCNT(0);                            // next tile landed (had whole compute)
    __builtin_amdgcn_s_barrier();
  }

  float4 cb4 = *(const float4*)(cadd + b * TTXT + sb * BN + tx * 4);
  float c0[4] = {cb4.x, cb4.y, cb4.z, cb4.w};
  float* ob = neg + (size_t)b * TFEAT * TTXT + (size_t)(tb * BM + ty * 8) * TTXT + sb * BN;
  #pragma unroll
  for (int i = 0; i < 8; ++i) {
    float4 o = {acc[i][0] + c0[0], acc[i][1] + c0[1], acc[i][2] + c0[2], acc[i][3] + c0[3]};
    *(float4*)(ob + (size_t)i * TTXT + tx * 4) = o;
  }
}

// ---------------------------------------------------------------------------
// Kernel C (R12): skewed-wavefront DP, KROWS 16 -> 32.
// R11: 6800 cy/phase but only ~500 cy of row work -> fixed per-phase cost
// (8-wave barrier convergence + waits) dominates. Halve the phase count
// (72 barriers vs 136) by doubling the window. Row body unchanged (lean,
// writelane-free). Arithmetic identical -> bit-exact path.
// ---------------------------------------------------------------------------
#define KROWS 32
#define NWIN  (TFEAT / KROWS)     // 64 windows
#define NMASKW (TTXT / KROWS)     // 16 masked windows

__device__ __forceinline__ float dpp_shr1(float v) {
  return __int_as_float(__builtin_amdgcn_update_dpp(
      __float_as_int(v), __float_as_int(v), 0x138 /*wave_shr:1*/, 0xF, 0xF, false));
}

template<bool MASKED>
__device__ __forceinline__ void dp_win(
    float& prev, const float (&cur)[KROWS], const float (&s_bnd)[KROWS],
    int y0, int tid, int lane, int w,
    unsigned long long (*bitsq)[8], float (*bndlds)[8][KROWS], int slot) {
  unsigned keep_lo = 0, keep_hi = 0;
  float bkeep = 0.0f;
  unsigned long long andm = (w == 0) ? ~1ull : ~0ull;   // x==0 never moves
  #pragma unroll
  for (int r = 0; r < KROWS; ++r) {
    float upd = dpp_shr1(prev);
    float up = (lane == 0) ? s_bnd[r] : upd;
    bool force = MASKED && (tid == y0 + r);
    bool gt = prev < up;
    unsigned long long m = __ballot(force || gt) & andm;  // uniform (SGPR pair)
    bool mine = (lane == r);
    keep_lo = mine ? (unsigned)m : keep_lo;
    keep_hi = mine ? (unsigned)(m >> 32) : keep_hi;
    float vc = force ? NEGINF : prev;
    prev = fmaxf(vc, up) + cur[r];
    float v63 = __int_as_float(
        __builtin_amdgcn_readlane(__float_as_int(prev), 63));  // uniform
    bkeep = mine ? v63 : bkeep;
  }
  if (lane < KROWS) {                    // one exec toggle per window
    bndlds[slot][w][lane] = bkeep;
    bitsq[y0 + lane][w] =
        ((unsigned long long)keep_hi << 32) | keep_lo;
  }
}

__device__ __forceinline__ void dp_phase(
    int p, float (&cur)[KROWS], float (&nxt)[KROWS],
    float& prev, const float* nb, int tid, int lane, int w,
    unsigned long long (*bitsq)[8], float (*bndlds)[8][KROWS]) {
  int i = p - w;                         // this wave's window this phase
  int j = i + 1;                         // window to prefetch
  if (j >= 1 && j < NWIN) {
    const float* base = nb + (size_t)(j * KROWS) * TTXT + tid;
    #pragma unroll
    for (int r = 0; r < KROWS; ++r) nxt[r] = base[(size_t)r * TTXT];
  }
  __builtin_amdgcn_sched_barrier(0);     // loads issued before compute
  if (i >= 0 && i < NWIN) {
    float s_bnd[KROWS];                  // hoisted boundary values
    if (w > 0) {
      float v    = bndlds[i % 3][w - 1][lane & (KROWS - 1)];
      float vend = bndlds[(i + 2) % 3][w - 1][KROWS - 1];
      s_bnd[0] = __int_as_float(__builtin_amdgcn_readfirstlane(__float_as_int(vend)));
      #pragma unroll
      for (int r = 1; r < KROWS; ++r)
        s_bnd[r] = __int_as_float(__builtin_amdgcn_readlane(__float_as_int(v), r - 1));
    } else {
      #pragma unroll
      for (int r = 0; r < KROWS; ++r) s_bnd[r] = NEGINF;
      if (i == 0) s_bnd[0] = 0.0f;       // y==0, x==0 edge
    }
    int y0 = i * KROWS;
    if (i < NMASKW) dp_win<true >(prev, cur, s_bnd, y0, tid, lane, w, bitsq, bndlds, i % 3);
    else            dp_win<false>(prev, cur, s_bnd, y0, tid, lane, w, bitsq, bndlds, i % 3);
  }
  asm volatile("s_waitcnt lgkmcnt(0)" ::: "memory");   // window writes drained
  __builtin_amdgcn_s_barrier();
  __builtin_amdgcn_sched_barrier(0);
}

__global__ __launch_bounds__(512, 1)
void k_dp(const float* __restrict__ neg, float* __restrict__ dur,
          int* __restrict__ idx_out, const float* __restrict__ x_mask) {
  __shared__ unsigned long long bitsq[TFEAT][8];   // 128 KiB decision bits
  __shared__ float bndlds[3][8][KROWS];            // 3 KiB boundary ring
  int b = blockIdx.x, tid = threadIdx.x;
  int lane = tid & 63, w = tid >> 6;
  const float* nb = neg + (size_t)b * TFEAT * TTXT;

  for (int t = tid; t < 3 * 8 * KROWS; t += 512) ((float*)bndlds)[t] = NEGINF;

  float A[KROWS], B[KROWS];
  {                                      // prologue: window 0 -> A (all waves)
    const float* base = nb + tid;
    #pragma unroll
    for (int r = 0; r < KROWS; ++r) A[r] = base[(size_t)r * TTXT];
  }
  __syncthreads();

  float prev = NEGINF;
  // per-wave parity rotation keeps nf-buffer indexing static
  if ((w & 1) == 0) {
    for (int p = 0; p < NWIN + 8; p += 2) {
      dp_phase(p,     A, B, prev, nb, tid, lane, w, bitsq, bndlds);
      dp_phase(p + 1, B, A, prev, nb, tid, lane, w, bitsq, bndlds);
    }
  } else {
    for (int p = 0; p < NWIN + 8; p += 2) {
      dp_phase(p,     B, A, prev, nb, tid, lane, w, bitsq, bndlds);
      dp_phase(p + 1, A, B, prev, nb, tid, lane, w, bitsq, bndlds);
    }
  }
  __syncthreads();

  // ---- serial backtrack (tid 0) with 8-row-ahead register ring: words
  // {W, W-1} of row y-8 prefetched at row y (idx drifts <= 8 -> always covered)
  if (tid == 0) {
    const float* xm = x_mask + (size_t)b * TTXT;
    const unsigned* bw = (const unsigned*)bitsq;   // [TFEAT][16] u32 view
    int idx = TTXT - 1, cnt = 0;
    unsigned uc[8], ul[8]; int wi[8];
    #pragma unroll
    for (int q = 0; q < 8; ++q) {        // rows 2040..2047 (slot q = y&7)
      uc[q] = bw[(2040 + q) * 16 + 15];
      ul[q] = bw[(2040 + q) * 16 + 14];
      wi[q] = 15;
    }
    for (int yb = 2040; yb >= 8; yb -= 8) {
      #pragma unroll
      for (int jj = 7; jj >= 0; --jj) {
        int y = yb + jj;                 // slot = jj (yb % 8 == 0)
        unsigned word = ((idx >> 5) == wi[jj]) ? uc[jj] : ul[jj];
        idx_out[b * TFEAT + y] = idx;
        cnt++;
        if ((word >> (idx & 31)) & 1u) {
          dur[b * TTXT + idx] = (float)cnt * xm[idx];
          cnt = 0; idx--;
        }
        int W = idx >> 5;                // refill slot jj for row y-8
        uc[jj] = bw[(y - 8) * 16 + W];
        ul[jj] = (W > 0) ? bw[(y - 8) * 16 + W - 1] : 0u;
        wi[jj] = W;
      }
    }
    #pragma unroll
    for (int jj = 7; jj >= 0; --jj) {    // tail rows 7..0
      int y = jj;
      unsigned word = ((idx >> 5) == wi[jj]) ? uc[jj] : ul[jj];
      idx_out[b * TFEAT + y] = idx;
      cnt++;
      if ((word >> (idx & 31)) & 1u) {
        dur[b * TTXT + idx] = (float)cnt * xm[idx];
        cnt = 0; idx--;
      }
    }
    dur[b * TTXT] = (float)cnt * xm[0];  // idx == 0 tail run
  }
}

// ---------------------------------------------------------------------------
// Kernel D: attn[b,y,x] = (x == idx[y]) * x_mask[b,x] * y_mask[b,y]
// ---------------------------------------------------------------------------
__global__ void k_attn(const int* __restrict__ idx_arr,
                       const float* __restrict__ x_mask,
                       const float* __restrict__ y_mask,
                       float* __restrict__ attn) {
  size_t gid = (size_t)blockIdx.x * 256 + threadIdx.x;
  size_t e = gid << 2;               // 4 floats per thread
  int b = (int)(e >> 20);            // TFEAT*TTXT = 2^20
  int rem = (int)(e & 1048575u);
  int y = rem >> 9;
  int x0 = rem & 511;
  int idx = idx_arr[b * TFEAT + y];
  float4 v = {0.f, 0.f, 0.f, 0.f};
  int d = idx - x0;
  if (d >= 0 && d < 4) {
    ((float*)&v)[d] = x_mask[b * TTXT + idx] * y_mask[b * TFEAT + y];
  }
  *(float4*)(attn + e) = v;
}

// ---------------------------------------------------------------------------
extern "C" void kernel_launch(void* const* d_in, const int* in_sizes, int n_in,
                              void* d_out, int out_size, void* d_ws, size_t ws_size,
                              hipStream_t stream) {
  const float* z_p    = (const float*)d_in[0];
  const float* m_p    = (const float*)d_in[1];
  const float* logs_p = (const float*)d_in[2];
  const float* x_mask = (const float*)d_in[3];
  const float* y_mask = (const float*)d_in[4];

  float* out  = (float*)d_out;
  float* attn = out;
  float* dur  = out + DUR_OFF;
  float* neg  = out + NEG_OFF;

  // W1/W2 scratch lives in the attn region (fully rewritten by k_attn later)
  float* w1s = attn;
  float* w2s = attn + (size_t)BATCH * CH * TTXT;      // 3,145,728 floats each

  // workspace: cadd (64 KiB) + idx array (256 KiB)
  float* cadd = (float*)d_ws;
  int*   idxa = (int*)((char*)d_ws + 65536);

  k_prep<<<(BATCH * CH * TTXT) / 256, 256, 0, stream>>>(m_p, logs_p, w1s, w2s);
  k_cadd<<<(BATCH * TTXT) / 256, 256, 0, stream>>>(m_p, logs_p, cadd);
  k_gemm<<<BATCH * (TFEAT / BM) * (TTXT / BN), 512, 0, stream>>>(z_p, w1s, w2s, cadd, neg);
  k_dp<<<BATCH, 512, 0, stream>>>(neg, dur, idxa, x_mask);
  k_attn<<<(int)(ATTN_ELEMS / 4 / 256), 256, 0, stream>>>(idxa, x_mask, y_mask, attn);
}

// Round 13
// 738.636 us; speedup vs baseline: 1.0824x; 1.0824x over previous
//
#include <hip/hip_runtime.h>
#include <math.h>

// Problem constants (fixed by the reference setup_inputs)
#define BATCH 32
#define CH    192
#define TFEAT 2048
#define TTXT  512
#define NEGINF (-1e9f)

#define ATTN_ELEMS ((size_t)BATCH * TFEAT * TTXT)   // 33,554,432
#define DUR_OFF    ATTN_ELEMS
#define NEG_OFF    (ATTN_ELEMS + (size_t)BATCH * TTXT)

__device__ __forceinline__ void gload_lds16(const float* g, float* l) {
  __builtin_amdgcn_global_load_lds(
      (const __attribute__((address_space(1))) void*)g,
      (__attribute__((address_space(3))) void*)l, 16, 0, 0);
}

#define VMCNT(n) asm volatile("s_waitcnt vmcnt(" #n ")" ::: "memory")

// ---------------------------------------------------------------------------
// Kernel P: W1[b,c,s] = m*exp(-2*logs), W2[b,c,s] = -0.5*exp(-2*logs)
// ---------------------------------------------------------------------------
__global__ void k_prep(const float* __restrict__ m_p,
                       const float* __restrict__ logs_p,
                       float* __restrict__ w1, float* __restrict__ w2) {
  int gid = blockIdx.x * 256 + threadIdx.x;    // 0 .. 3,145,727
  float m = m_p[gid];
  float l = logs_p[gid];
  float r = __expf(-2.0f * l);
  w1[gid] = m * r;
  w2[gid] = -0.5f * r;
}

// ---------------------------------------------------------------------------
// Kernel A: cadd[b][s] = sum_c(-0.5*log(2pi) - logs) + sum_c(-0.5*m^2*r)
// ---------------------------------------------------------------------------
__global__ void k_cadd(const float* __restrict__ m_p,
                       const float* __restrict__ logs_p,
                       float* __restrict__ cadd) {
  int gid = blockIdx.x * 256 + threadIdx.x;        // 0 .. 16383
  int b = gid >> 9, s = gid & (TTXT - 1);
  const float* mp = m_p    + (size_t)b * CH * TTXT + s;
  const float* lp = logs_p + (size_t)b * CH * TTXT + s;
  float acc = -0.5f * 1.8378770664093453f * (float)CH;   // -C/2 * log(2*pi)
  #pragma unroll 4
  for (int c = 0; c < CH; ++c) {
    float l = lp[(size_t)c * TTXT];
    float m = mp[(size_t)c * TTXT];
    float r = __expf(-2.0f * l);
    acc -= l + 0.5f * m * m * r;
  }
  cadd[gid] = acc;
}

// ---------------------------------------------------------------------------
// Kernel B: fp32 vector GEMM, 512 threads, acc[8][4], depth-1 fragment
// pipeline + 2-phase LDS double-buffer. UNCHANGED from R12 (~315us,
// no spill at VGPR 112). Same ko/kk/fma order -> neg bit-identical.
// ---------------------------------------------------------------------------
#define BM 128
#define BN 128
#define BK 16

struct Frag { float a[8]; float p[4]; float q[4]; };

__global__ __launch_bounds__(512)
void k_gemm(const float* __restrict__ z_p,
            const float* __restrict__ w1g, const float* __restrict__ w2g,
            const float* __restrict__ cadd, float* __restrict__ neg) {
  __shared__ float Az[2][BK][BM];
  __shared__ float B1[2][BK][BN];
  __shared__ float B2[2][BK][BN];

  // chunked XCD swizzle (2048 blocks, 8 XCDs, 256 per chunk; bijective)
  int blk = (blockIdx.x & 7) * 256 + (blockIdx.x >> 3);
  int sb = blk & 3;            // TTXT/BN = 4
  int tb = (blk >> 2) & 15;    // TFEAT/BM = 16
  int b  = blk >> 6;
  int tid = threadIdx.x;
  int tx = tid & 31;           // col group: 4 cols at tx*4
  int ty = tid >> 5;           // row group: 8 rows at ty*8  (0..15)
  int wid  = tid >> 6;         // wave 0..7
  int lane = tid & 63;
  int lr = lane >> 5;          // row-within-pair
  int lc = (lane & 31) * 4;    // col (float4 granularity)

  const float* zb  = z_p + (size_t)b * CH * TFEAT + (size_t)tb * BM;
  const float* w1b = w1g + (size_t)b * CH * TTXT  + (size_t)sb * BN;
  const float* w2b = w2g + (size_t)b * CH * TTXT  + (size_t)sb * BN;

  auto STAGE = [&](int buf, int ko) {
    int kr = ko * BK + 2 * wid + lr;     // per-lane global k-row
    int kd = 2 * wid;                    // wave-uniform LDS row base
    gload_lds16(zb  + (size_t)kr * TFEAT + lc, &Az[buf][kd][0]);
    gload_lds16(w1b + (size_t)kr * TTXT  + lc, &B1[buf][kd][0]);
    gload_lds16(w2b + (size_t)kr * TTXT  + lc, &B2[buf][kd][0]);
  };
  auto LOADF = [&](Frag& f, int cur, int kk) {
    float4 a0 = *(const float4*)&Az[cur][kk][ty * 8];
    float4 a1 = *(const float4*)&Az[cur][kk][ty * 8 + 4];
    float4 p  = *(const float4*)&B1[cur][kk][tx * 4];
    float4 q  = *(const float4*)&B2[cur][kk][tx * 4];
    f.a[0]=a0.x; f.a[1]=a0.y; f.a[2]=a0.z; f.a[3]=a0.w;
    f.a[4]=a1.x; f.a[5]=a1.y; f.a[6]=a1.z; f.a[7]=a1.w;
    f.p[0]=p.x;  f.p[1]=p.y;  f.p[2]=p.z;  f.p[3]=p.w;
    f.q[0]=q.x;  f.q[1]=q.y;  f.q[2]=q.z;  f.q[3]=q.w;
  };

  float acc[8][4];
  #pragma unroll
  for (int i = 0; i < 8; ++i)
    #pragma unroll
    for (int j = 0; j < 4; ++j) acc[i][j] = 0.0f;

  auto FMAF = [&](const Frag& f) {
    #pragma unroll
    for (int i = 0; i < 8; ++i)
      #pragma unroll
      for (int j = 0; j < 4; ++j)
        acc[i][j] = fmaf(f.a[i], fmaf(f.a[i], f.q[j], f.p[j]), acc[i][j]);
  };

  STAGE(0, 0);
  VMCNT(0);
  __builtin_amdgcn_s_barrier();

  for (int ko = 0; ko < CH / BK; ++ko) {
    int cur = ko & 1;
    if (ko + 1 < CH / BK) STAGE(cur ^ 1, ko + 1);   // prefetch next tile

    Frag f0, f1;
    LOADF(f0, cur, 0);
    #pragma unroll
    for (int kk = 0; kk < BK; kk += 2) {
      LOADF(f1, cur, kk + 1);            // reads hide under FMAF(f0)
      FMAF(f0);
      __builtin_amdgcn_sched_barrier(0);
      if (kk + 2 < BK) LOADF(f0, cur, kk + 2);
      FMAF(f1);
      __builtin_amdgcn_sched_barrier(0);
    }
    VMCNT(0);                            // next tile landed (had whole compute)
    __builtin_amdgcn_s_barrier();
  }

  float4 cb4 = *(const float4*)(cadd + b * TTXT + sb * BN + tx * 4);
  float c0[4] = {cb4.x, cb4.y, cb4.z, cb4.w};
  float* ob = neg + (size_t)b * TFEAT * TTXT + (size_t)(tb * BM + ty * 8) * TTXT + sb * BN;
  #pragma unroll
  for (int i = 0; i < 8; ++i) {
    float4 o = {acc[i][0] + c0[0], acc[i][1] + c0[1], acc[i][2] + c0[2], acc[i][3] + c0[3]};
    *(float4*)(ob + (size_t)i * TTXT + tx * 4) = o;
  }
}

// ---------------------------------------------------------------------------
// Kernel C (R13): skewed-wavefront DP with per-wave LDS slice-ring.
// R12 ablation: per-row cost ~390cy invariant to KROWS/body -> theory: the
// per-row per-wave 256B global loads (8 waves hammering one 2KB row = same
// HBM channels) serialize. R13: wave w stages ITS OWN 64-col slice of window
// i+3 via 4x contiguous-1KB global_load_lds (per-lane gathered src), ring
// depth 4, counted VMCNT(12) (producer==consumer -> per-wave exact, no
// barrier needed for nf). bits move to GLOBAL (attn region, dead zone) to
// free LDS; backtrack reads them with a 16-deep register ring.
// Row body / s_bnd / barrier-per-window: verbatim R11 -> bit-exact path.
// ---------------------------------------------------------------------------
#define KROWS 16
#define NWIN  (TFEAT / KROWS)     // 128 windows
#define NMASKW (TTXT / KROWS)     // 32 masked windows

__device__ __forceinline__ float dpp_shr1(float v) {
  return __int_as_float(__builtin_amdgcn_update_dpp(
      __float_as_int(v), __float_as_int(v), 0x138 /*wave_shr:1*/, 0xF, 0xF, false));
}

__global__ __launch_bounds__(512, 1)
void k_dp(const float* __restrict__ neg, float* __restrict__ dur,
          int* __restrict__ idx_out, const float* __restrict__ x_mask,
          unsigned long long* __restrict__ gbits_all) {
  __shared__ float ring[8][4][KROWS][64];   // 131072 B (per-wave slice ring)
  __shared__ float bndlds[3][8][KROWS];     //   1536 B (boundary ring)
  int b = blockIdx.x, tid = threadIdx.x;
  int lane = tid & 63, w = tid >> 6;
  const float* nb = neg + (size_t)b * TFEAT * TTXT;
  unsigned long long* gbits = gbits_all + (size_t)b * 8 * TFEAT;  // [8][2048]

  if (tid < 3 * 8 * KROWS) ((float*)bndlds)[tid] = NEGINF;

  // per-lane gather offset: lane l -> row (l>>4), col w*64 + (l&15)*4
  int off0 = (lane >> 4) * TTXT + (lane & 15) * 4 + w * 64;
  auto stage = [&](int j) {               // stage this wave's slice of window j
    int slot = j & 3;
    const float* s0 = nb + (size_t)(j * KROWS) * TTXT + off0;
    gload_lds16(s0,             &ring[w][slot][0][0]);
    gload_lds16(s0 + 4 * TTXT,  &ring[w][slot][4][0]);
    gload_lds16(s0 + 8 * TTXT,  &ring[w][slot][8][0]);
    gload_lds16(s0 + 12 * TTXT, &ring[w][slot][12][0]);
  };

  stage(0); stage(1); stage(2);
  __syncthreads();                        // drains prologue loads + bndlds init

  float prev = NEGINF;
  for (int p = 0; p < NWIN + 8; ++p) {
    int i = p - w;                        // this wave's window this phase
    if (i >= 0 && i + 3 < NWIN) stage(i + 3);
    VMCNT(12);                            // window i's slice loads landed
    asm volatile("s_waitcnt lgkmcnt(0)" ::: "memory");
    __builtin_amdgcn_s_barrier();         // bndlds(prev phase) visible
    __builtin_amdgcn_sched_barrier(0);

    if (i >= 0 && i < NWIN) {
      // hoisted boundary values (wave-uniform)
      float s_bnd[KROWS];
      if (w > 0) {
        float v   = bndlds[i % 3][w - 1][lane & 15];
        float v15 = bndlds[(i + 2) % 3][w - 1][15];
        s_bnd[0] = __int_as_float(__builtin_amdgcn_readfirstlane(__float_as_int(v15)));
        #pragma unroll
        for (int r = 1; r < KROWS; ++r)
          s_bnd[r] = __int_as_float(__builtin_amdgcn_readlane(__float_as_int(v), r - 1));
      } else {
        #pragma unroll
        for (int r = 0; r < KROWS; ++r) s_bnd[r] = NEGINF;
        if (i == 0) s_bnd[0] = 0.0f;      // y==0, x==0 edge
      }
      // own-slice nf (LDS, conflict-free, batched)
      float cur[KROWS];
      #pragma unroll
      for (int r = 0; r < KROWS; ++r) cur[r] = ring[w][i & 3][r][lane];

      int y0 = i * KROWS;
      bool masked = (i < NMASKW);
      unsigned keep_lo = 0, keep_hi = 0;
      float bkeep = 0.0f;
      unsigned long long andm = (w == 0) ? ~1ull : ~0ull;   // x==0 never moves
      #pragma unroll
      for (int r = 0; r < KROWS; ++r) {
        float upd = dpp_shr1(prev);
        float up = (lane == 0) ? s_bnd[r] : upd;
        bool force = masked && (tid == y0 + r);
        bool gt = prev < up;
        unsigned long long m = __ballot(force || gt) & andm;  // uniform
        bool mine = (lane == r);
        keep_lo = mine ? (unsigned)m : keep_lo;
        keep_hi = mine ? (unsigned)(m >> 32) : keep_hi;
        float vc = force ? NEGINF : prev;
        prev = fmaxf(vc, up) + cur[r];
        float v63 = __int_as_float(
            __builtin_amdgcn_readlane(__float_as_int(prev), 63));  // uniform
        bkeep = mine ? v63 : bkeep;
      }
      if (lane < KROWS) {                 // one exec toggle per window
        bndlds[i % 3][w][lane] = bkeep;
        gbits[(size_t)w * TFEAT + y0 + lane] =
            ((unsigned long long)keep_hi << 32) | keep_lo;   // 128B contiguous
      }
    }
  }
  VMCNT(0);
  __syncthreads();                        // gbits stores drained + visible

  // ---- serial backtrack (tid 0), 16-deep register ring over global bits.
  // u64 q = x>>6 selects the wave word; words {q, q-1} always cover the
  // <=16 idx drift between prefetch and use.
  if (tid == 0) {
    const float* xm = x_mask + (size_t)b * TTXT;
    int idx = TTXT - 1, cnt = 0;
    unsigned long long ua[16], ub[16]; int qi[16];
    #pragma unroll
    for (int q16 = 0; q16 < 16; ++q16) {  // rows 2032..2047 (slot = y&15)
      ua[q16] = gbits[(size_t)7 * TFEAT + 2032 + q16];
      ub[q16] = gbits[(size_t)6 * TFEAT + 2032 + q16];
      qi[q16] = 7;
    }
    for (int yb = 2032; yb >= 16; yb -= 16) {
      #pragma unroll
      for (int jj = 15; jj >= 0; --jj) {
        int y = yb + jj;                  // slot = jj (yb % 16 == 0)
        unsigned long long w64 = ((idx >> 6) == qi[jj]) ? ua[jj] : ub[jj];
        idx_out[b * TFEAT + y] = idx;
        cnt++;
        if ((w64 >> (idx & 63)) & 1ull) {
          dur[b * TTXT + idx] = (float)cnt * xm[idx];
          cnt = 0; idx--;
        }
        int q = idx >> 6;                 // refill slot jj for row y-16
        int qm = q > 0 ? q - 1 : 0;
        ua[jj] = gbits[(size_t)q  * TFEAT + (y - 16)];
        ub[jj] = gbits[(size_t)qm * TFEAT + (y - 16)];
        qi[jj] = q;
      }
    }
    #pragma unroll
    for (int jj = 15; jj >= 0; --jj) {    // tail rows 15..0
      int y = jj;
      unsigned long long w64 = ((idx >> 6) == qi[jj]) ? ua[jj] : ub[jj];
      idx_out[b * TFEAT + y] = idx;
      cnt++;
      if ((w64 >> (idx & 63)) & 1ull) {
        dur[b * TTXT + idx] = (float)cnt * xm[idx];
        cnt = 0; idx--;
      }
    }
    dur[b * TTXT] = (float)cnt * xm[0];   // idx == 0 tail run
  }
}

// ---------------------------------------------------------------------------
// Kernel D: attn[b,y,x] = (x == idx[y]) * x_mask[b,x] * y_mask[b,y]
// ---------------------------------------------------------------------------
__global__ void k_attn(const int* __restrict__ idx_arr,
                       const float* __restrict__ x_mask,
                       const float* __restrict__ y_mask,
                       float* __restrict__ attn) {
  size_t gid = (size_t)blockIdx.x * 256 + threadIdx.x;
  size_t e = gid << 2;               // 4 floats per thread
  int b = (int)(e >> 20);            // TFEAT*TTXT = 2^20
  int rem = (int)(e & 1048575u);
  int y = rem >> 9;
  int x0 = rem & 511;
  int idx = idx_arr[b * TFEAT + y];
  float4 v = {0.f, 0.f, 0.f, 0.f};
  int d = idx - x0;
  if (d >= 0 && d < 4) {
    ((float*)&v)[d] = x_mask[b * TTXT + idx] * y_mask[b * TFEAT + y];
  }
  *(float4*)(attn + e) = v;
}

// ---------------------------------------------------------------------------
extern "C" void kernel_launch(void* const* d_in, const int* in_sizes, int n_in,
                              void* d_out, int out_size, void* d_ws, size_t ws_size,
                              hipStream_t stream) {
  const float* z_p    = (const float*)d_in[0];
  const float* m_p    = (const float*)d_in[1];
  const float* logs_p = (const float*)d_in[2];
  const float* x_mask = (const float*)d_in[3];
  const float* y_mask = (const float*)d_in[4];

  float* out  = (float*)d_out;
  float* attn = out;
  float* dur  = out + DUR_OFF;
  float* neg  = out + NEG_OFF;

  // scratch living in the attn region (fully rewritten by k_attn at the end):
  //   w1s/w2s: GEMM weights (consumed by k_gemm, before k_dp)
  //   gbits:   DP decision bits (written+read by k_dp)  [4 MB]
  float* w1s = attn;
  float* w2s = attn + (size_t)BATCH * CH * TTXT;      // 3,145,728 floats each
  unsigned long long* gbits =
      (unsigned long long*)(attn + 2 * (size_t)BATCH * CH * TTXT);

  // workspace: cadd (64 KiB) + idx array (256 KiB)
  float* cadd = (float*)d_ws;
  int*   idxa = (int*)((char*)d_ws + 65536);

  k_prep<<<(BATCH * CH * TTXT) / 256, 256, 0, stream>>>(m_p, logs_p, w1s, w2s);
  k_cadd<<<(BATCH * TTXT) / 256, 256, 0, stream>>>(m_p, logs_p, cadd);
  k_gemm<<<BATCH * (TFEAT / BM) * (TTXT / BN), 512, 0, stream>>>(z_p, w1s, w2s, cadd, neg);
  k_dp<<<BATCH, 512, 0, stream>>>(neg, dur, idxa, x_mask, gbits);
  k_attn<<<(int)(ATTN_ELEMS / 4 / 256), 256, 0, stream>>>(idxa, x_mask, y_mask, attn);
}